// Round 5
// baseline (446.302 us; speedup 1.0000x reference)
//
#include <hip/hip_runtime.h>
#include <hip/hip_bf16.h>

#define B_  4096
#define F_  26
#define E_  64
#define D_  1664
#define N1_ 1024
#define N2_ 512
#define N3_ 256

typedef __attribute__((ext_vector_type(8))) __bf16 bf16x8;
typedef __attribute__((ext_vector_type(4))) float  f32x4;

__device__ __forceinline__ unsigned short f2b(float x) {
    __hip_bfloat16 h = __float2bfloat16(x);
    return __builtin_bit_cast(unsigned short, h);
}
__device__ __forceinline__ float b2f(unsigned short u) {
    return __uint_as_float(((unsigned)u) << 16);
}

// async global->LDS DMA: pass WAVE-UNIFORM lds base; HW places lane i at base + i*16B
__device__ __forceinline__ void async_load16(const void* g, void* l) {
    __builtin_amdgcn_global_load_lds(
        (const __attribute__((address_space(1))) void*)g,
        (__attribute__((address_space(3))) void*)l,
        16, 0, 0);
}

__device__ __forceinline__ f32x4 mfma16(bf16x8 a, bf16x8 b, f32x4 c) {
    return __builtin_amdgcn_mfma_f32_16x16x32_bf16(a, b, c, 0, 0, 0);
}

// ---------------- fused gather + cross + head-partial  (+ weight transpose)
// Blocks [0, B_): one block per batch row, R0's low-register body (per-round
// weight loads), double-buffered red -> 1 barrier per reduction round.
// Blocks [B_, B_+2304): 32x32 f32->bf16 transpose tiles of w1/w2/w3.
__global__ __launch_bounds__(256) void gather_cross_transpose_kernel(
        const int* __restrict__ ids, const float* __restrict__ emb,
        const float* __restrict__ cw, const float* __restrict__ cb,
        const float* __restrict__ out_w,
        unsigned short* __restrict__ x0out, float* __restrict__ partial,
        const float* __restrict__ w1, const float* __restrict__ w2,
        const float* __restrict__ w3,
        unsigned short* __restrict__ o1, unsigned short* __restrict__ o2,
        unsigned short* __restrict__ o3)
{
    __shared__ int   sid[F_];
    __shared__ float red[2][4];
    __shared__ float tile[32][33];

    if (blockIdx.x >= B_) {
        // ------------------------- transpose branch
        const int bid = blockIdx.x - B_;
        const float* in; unsigned short* out; int K, N, lg, t0;
        if (bid < 1664)      { in = w1; out = o1; K = D_;  N = N1_; lg = 5; t0 = 0;    }
        else if (bid < 2176) { in = w2; out = o2; K = N1_; N = N2_; lg = 4; t0 = 1664; }
        else                 { in = w3; out = o3; K = N2_; N = N3_; lg = 3; t0 = 2176; }
        const int tl = bid - t0;
        const int n0 = (tl & ((1 << lg) - 1)) * 32;
        const int k0 = (tl >> lg) * 32;
        const int tc = threadIdx.x & 31, tr = threadIdx.x >> 5;
        #pragma unroll
        for (int p = 0; p < 4; p++)
            tile[tr + p * 8][tc] = in[(size_t)(k0 + tr + p * 8) * N + n0 + tc];
        __syncthreads();
        #pragma unroll
        for (int p = 0; p < 4; p++) {
            const int n = tr + p * 8;
            out[(size_t)(n0 + n) * K + k0 + tc] = f2b(tile[tc][n]);
        }
        return;
    }

    // ------------------------- gather + cross branch (R0 body)
    const int b = blockIdx.x;
    const int t = threadIdx.x;
    const int lane = t & 63, w = t >> 6;
    constexpr int C4 = D_ / 4;           // 416 float4 chunks per row

    if (t < F_) sid[t] = ids[b * F_ + t];
    __syncthreads();

    const float4* emb4 = (const float4*)emb;
    const float4* cw4  = (const float4*)cw;
    const float4* cb4  = (const float4*)cb;
    const float4* ow4  = (const float4*)out_w;

    float4 x0v[2], xv[2];
    #pragma unroll
    for (int j = 0; j < 2; j++) {
        const int c = t + j * 256;
        float4 v = make_float4(0.f, 0.f, 0.f, 0.f);
        if (c < C4) {
            const int f = c >> 4;                       // 16 chunks per field
            v = emb4[(size_t)sid[f] * 16 + (c & 15)];
            ushort4 o;
            o.x = f2b(v.x); o.y = f2b(v.y); o.z = f2b(v.z); o.w = f2b(v.w);
            ((ushort4*)x0out)[(size_t)b * C4 + c] = o;
        }
        x0v[j] = v; xv[j] = v;
    }
    for (int i = 0; i < 3; i++) {
        float s = 0.f;
        #pragma unroll
        for (int j = 0; j < 2; j++) {
            const int c = t + j * 256;
            if (c < C4) {
                const float4 wv = cw4[i * C4 + c];
                s += xv[j].x * wv.x + xv[j].y * wv.y + xv[j].z * wv.z + xv[j].w * wv.w;
            }
        }
        #pragma unroll
        for (int off = 32; off > 0; off >>= 1) s += __shfl_down(s, off, 64);
        if (lane == 0) red[i & 1][w] = s;
        __syncthreads();
        const float st = red[i & 1][0] + red[i & 1][1] + red[i & 1][2] + red[i & 1][3];
        #pragma unroll
        for (int j = 0; j < 2; j++) {
            const int c = t + j * 256;
            if (c < C4) {
                const float4 bv = cb4[i * C4 + c];
                xv[j].x = x0v[j].x * st + bv.x + xv[j].x;
                xv[j].y = x0v[j].y * st + bv.y + xv[j].y;
                xv[j].z = x0v[j].z * st + bv.z + xv[j].z;
                xv[j].w = x0v[j].w * st + bv.w + xv[j].w;
            }
        }
    }
    float s = 0.f;
    #pragma unroll
    for (int j = 0; j < 2; j++) {
        const int c = t + j * 256;
        if (c < C4) {
            const float4 wv = ow4[c];
            s += xv[j].x * wv.x + xv[j].y * wv.y + xv[j].z * wv.z + xv[j].w * wv.w;
        }
    }
    #pragma unroll
    for (int off = 32; off > 0; off >>= 1) s += __shfl_down(s, off, 64);
    if (lane == 0) red[1][w] = s;
    __syncthreads();
    if (t == 0) partial[b] = red[1][0] + red[1][1] + red[1][2] + red[1][3];
}

// ------------------------------------------------------------- MFMA GEMM
// C[M,N] = relu(A[M,K] @ Bt[N,K]^T + bias). bf16 in/out, fp32 acc.
// 16x16x32 MFMA, 4 waves (2x2), KU=BKC/32 slabs per barrier pair.
// Grid (N/BN, M/BM), M/BM divisible by 8 (XCD swizzle). K divisible by BKC.
template<int BM, int BN, int BKC>
__global__ __launch_bounds__(256, 4) void gemm_bias_relu(
        const unsigned short* __restrict__ A,
        const unsigned short* __restrict__ Bt,
        const float* __restrict__ bias,
        unsigned short* __restrict__ C,
        int M, int N, int K)
{
    constexpr int KU = BKC / 32;
    constexpr int WM = BM / 2, WN = BN / 2;
    constexpr int TI = WM / 16, TJ = WN / 16;
    constexpr int nA = BM / 16, nB = BN / 16, nAB = nA + nB;
    constexpr int TOTC = KU * nAB;          // 1KB chunks per barrier period
    static_assert(TOTC % 4 == 0, "chunk loop assumes 4-wave coverage");

    __shared__ unsigned short sA[KU * BM * 32];
    __shared__ unsigned short sB[KU * BN * 32];

    const int t    = threadIdx.x;
    const int lane = t & 63;
    const int w    = t >> 6;

    // XCD-aware swizzle: xcd = i%8 owns a contiguous band of M-tiles
    const int i    = blockIdx.y * gridDim.x + blockIdx.x;
    const int xcd  = i & 7;
    const int s    = i >> 3;
    const int ypg  = gridDim.y >> 3;
    const int ty   = xcd * ypg + s / gridDim.x;
    const int tx   = s - (s / gridDim.x) * gridDim.x;
    const int m0   = ty * BM;
    const int n0   = tx * BN;
    const int wm   = (w >> 1) * WM;
    const int wn   = (w & 1) * WN;

    const int srow = lane >> 2;        // 0..15 row within chunk
    const int scol = (lane & 3) * 8;   // 0,8,16,24 elem col within slab

    f32x4 acc[TI][TJ] = {};

    for (int k0 = 0; k0 < K; k0 += BKC) {
        #pragma unroll
        for (int c0 = 0; c0 < TOTC; c0 += 4) {
            const int c = c0 + w;
            const int u = c / nAB;              // slab (wave-uniform)
            const int r = c - u * nAB;
            if (r < nA) {
                const unsigned short* g =
                    A + (size_t)(m0 + r * 16 + srow) * K + k0 + u * 32 + scol;
                async_load16(g, &sA[u * BM * 32 + r * 512]);
            } else {
                const int rb = r - nA;
                const unsigned short* g =
                    Bt + (size_t)(n0 + rb * 16 + srow) * K + k0 + u * 32 + scol;
                async_load16(g, &sB[u * BN * 32 + rb * 512]);
            }
        }
        __syncthreads();

        #pragma unroll
        for (int u = 0; u < KU; u++) {
            bf16x8 af[TI], bf[TJ];
            #pragma unroll
            for (int ii = 0; ii < TI; ii++)
                af[ii] = *(const bf16x8*)
                    &sA[u * BM * 32 + (wm + ii * 16 + (lane & 15)) * 32 + (lane >> 4) * 8];
            #pragma unroll
            for (int j = 0; j < TJ; j++)
                bf[j] = *(const bf16x8*)
                    &sB[u * BN * 32 + (wn + j * 16 + (lane & 15)) * 32 + (lane >> 4) * 8];
            #pragma unroll
            for (int ii = 0; ii < TI; ii++)
                #pragma unroll
                for (int j = 0; j < TJ; j++)
                    acc[ii][j] = mfma16(af[ii], bf[j], acc[ii][j]);
        }
        __syncthreads();
    }

    // epilogue: C/D layout col=lane&15, row=(lane>>4)*4+reg
    #pragma unroll
    for (int ii = 0; ii < TI; ii++) {
        const int r0 = m0 + wm + ii * 16 + (lane >> 4) * 4;
        #pragma unroll
        for (int j = 0; j < TJ; j++) {
            const int col = n0 + wn + j * 16 + (lane & 15);
            const float bv = bias[col];
            #pragma unroll
            for (int r = 0; r < 4; r++) {
                float v = acc[ii][j][r] + bv;
                v = fmaxf(v, 0.f);
                C[(size_t)(r0 + r) * N + col] = f2b(v);
            }
        }
    }
}

// ---------------------------------------------------------------- head
__global__ __launch_bounds__(256) void head_kernel(
        const float* __restrict__ partial, const unsigned short* __restrict__ h3,
        const float* __restrict__ out_w, const float* __restrict__ out_b,
        float* __restrict__ out)
{
    const int gw   = (blockIdx.x * 256 + threadIdx.x) >> 6;  // one wave per row
    const int lane = threadIdx.x & 63;
    if (gw >= B_) return;
    float s = 0.f;
    #pragma unroll
    for (int q = 0; q < 4; q++) {
        const int j = lane + q * 64;
        s += b2f(h3[(size_t)gw * N3_ + j]) * out_w[D_ + j];
    }
    #pragma unroll
    for (int off = 32; off > 0; off >>= 1) s += __shfl_down(s, off, 64);
    if (lane == 0) {
        const float logit = partial[gw] + s + out_b[0];
        out[gw] = 1.f / (1.f + expf(-logit));
    }
}

extern "C" void kernel_launch(void* const* d_in, const int* in_sizes, int n_in,
                              void* d_out, int out_size, void* d_ws, size_t ws_size,
                              hipStream_t stream)
{
    (void)in_sizes; (void)n_in; (void)out_size; (void)ws_size;
    const int*   ids     = (const int*)  d_in[0];
    const float* emb     = (const float*)d_in[1];
    const float* cross_w = (const float*)d_in[2];
    const float* cross_b = (const float*)d_in[3];
    const float* w1      = (const float*)d_in[4];
    const float* b1      = (const float*)d_in[5];
    const float* w2      = (const float*)d_in[6];
    const float* b2      = (const float*)d_in[7];
    const float* w3      = (const float*)d_in[8];
    const float* b3      = (const float*)d_in[9];
    const float* out_w   = (const float*)d_in[10];
    const float* out_b   = (const float*)d_in[11];
    float* out = (float*)d_out;

    char* p = (char*)d_ws;
    auto alloc = [&](size_t bytes) {
        char* r = p; p += (bytes + 255) & ~(size_t)255; return r;
    };
    unsigned short* x0b = (unsigned short*)alloc((size_t)B_ * D_ * 2);
    unsigned short* w1t = (unsigned short*)alloc((size_t)D_ * N1_ * 2);
    unsigned short* w2t = (unsigned short*)alloc((size_t)N1_ * N2_ * 2);
    unsigned short* w3t = (unsigned short*)alloc((size_t)N2_ * N3_ * 2);
    unsigned short* h1  = (unsigned short*)alloc((size_t)B_ * N1_ * 2);
    unsigned short* h2  = (unsigned short*)alloc((size_t)B_ * N2_ * 2);
    unsigned short* h3  = (unsigned short*)alloc((size_t)B_ * N3_ * 2);
    float* partial      = (float*)alloc((size_t)B_ * 4);

    // ---- TIMING PROBE (R4): run the full idempotent pipeline TWICE.
    // dur = fixed_overhead + 2*t_ours; vs R2's fixed + t_ours = 378.
    // Decodes how much of the 378 us is actually our kernels.
    for (int rep = 0; rep < 2; rep++) {
        gather_cross_transpose_kernel<<<B_ + 2304, 256, 0, stream>>>(
            ids, emb, cross_w, cross_b, out_w, x0b, partial,
            w1, w2, w3, w1t, w2t, w3t);

        gemm_bias_relu<64, 64, 128><<<dim3(N1_ / 64, B_ / 64), 256, 0, stream>>>(
            x0b, w1t, b1, h1, B_, N1_, D_);
        gemm_bias_relu<64, 32, 128><<<dim3(N2_ / 32, B_ / 64), 256, 0, stream>>>(
            h1, w2t, b2, h2, B_, N2_, N1_);
        gemm_bias_relu<32, 32, 128><<<dim3(N3_ / 32, B_ / 32), 256, 0, stream>>>(
            h2, w3t, b3, h3, B_, N3_, N2_);

        head_kernel<<<B_ / 4, 256, 0, stream>>>(partial, h3, out_w, out_b, out);
    }
}

// Round 7
// 371.554 us; speedup vs baseline: 1.2012x; 1.2012x over previous
//
#include <hip/hip_runtime.h>
#include <hip/hip_bf16.h>

#define B_  4096
#define F_  26
#define E_  64
#define D_  1664
#define N1_ 1024
#define N2_ 512
#define N3_ 256

typedef __attribute__((ext_vector_type(8))) __bf16 bf16x8;
typedef __attribute__((ext_vector_type(4))) float  f32x4;

__device__ __forceinline__ unsigned short f2b(float x) {
    __hip_bfloat16 h = __float2bfloat16(x);
    return __builtin_bit_cast(unsigned short, h);
}
__device__ __forceinline__ float b2f(unsigned short u) {
    return __uint_as_float(((unsigned)u) << 16);
}

// async global->LDS DMA: pass WAVE-UNIFORM lds base; HW places lane i at base + i*16B
__device__ __forceinline__ void async_load16(const void* g, void* l) {
    __builtin_amdgcn_global_load_lds(
        (const __attribute__((address_space(1))) void*)g,
        (__attribute__((address_space(3))) void*)l,
        16, 0, 0);
}

__device__ __forceinline__ f32x4 mfma16(bf16x8 a, bf16x8 b, f32x4 c) {
    return __builtin_amdgcn_mfma_f32_16x16x32_bf16(a, b, c, 0, 0, 0);
}

// ---------------- fused gather + cross + head-partial  (+ weight transpose)
__global__ __launch_bounds__(256) void gather_cross_transpose_kernel(
        const int* __restrict__ ids, const float* __restrict__ emb,
        const float* __restrict__ cw, const float* __restrict__ cb,
        const float* __restrict__ out_w,
        unsigned short* __restrict__ x0out, float* __restrict__ partial,
        const float* __restrict__ w1, const float* __restrict__ w2,
        const float* __restrict__ w3,
        unsigned short* __restrict__ o1, unsigned short* __restrict__ o2,
        unsigned short* __restrict__ o3)
{
    __shared__ int   sid[F_];
    __shared__ float red[2][4];
    __shared__ float tile[32][33];

    if (blockIdx.x >= B_) {
        // ------------------------- transpose branch
        const int bid = blockIdx.x - B_;
        const float* in; unsigned short* out; int K, N, lg, t0;
        if (bid < 1664)      { in = w1; out = o1; K = D_;  N = N1_; lg = 5; t0 = 0;    }
        else if (bid < 2176) { in = w2; out = o2; K = N1_; N = N2_; lg = 4; t0 = 1664; }
        else                 { in = w3; out = o3; K = N2_; N = N3_; lg = 3; t0 = 2176; }
        const int tl = bid - t0;
        const int n0 = (tl & ((1 << lg) - 1)) * 32;
        const int k0 = (tl >> lg) * 32;
        const int tc = threadIdx.x & 31, tr = threadIdx.x >> 5;
        #pragma unroll
        for (int p = 0; p < 4; p++)
            tile[tr + p * 8][tc] = in[(size_t)(k0 + tr + p * 8) * N + n0 + tc];
        __syncthreads();
        #pragma unroll
        for (int p = 0; p < 4; p++) {
            const int n = tr + p * 8;
            out[(size_t)(n0 + n) * K + k0 + tc] = f2b(tile[tc][n]);
        }
        return;
    }

    // ------------------------- gather + cross branch
    const int b = blockIdx.x;
    const int t = threadIdx.x;
    const int lane = t & 63, w = t >> 6;
    constexpr int C4 = D_ / 4;           // 416 float4 chunks per row

    if (t < F_) sid[t] = ids[b * F_ + t];
    __syncthreads();

    const float4* emb4 = (const float4*)emb;
    const float4* cw4  = (const float4*)cw;
    const float4* cb4  = (const float4*)cb;
    const float4* ow4  = (const float4*)out_w;

    float4 x0v[2], xv[2];
    #pragma unroll
    for (int j = 0; j < 2; j++) {
        const int c = t + j * 256;
        float4 v = make_float4(0.f, 0.f, 0.f, 0.f);
        if (c < C4) {
            const int f = c >> 4;                       // 16 chunks per field
            v = emb4[(size_t)sid[f] * 16 + (c & 15)];
            ushort4 o;
            o.x = f2b(v.x); o.y = f2b(v.y); o.z = f2b(v.z); o.w = f2b(v.w);
            ((ushort4*)x0out)[(size_t)b * C4 + c] = o;
        }
        x0v[j] = v; xv[j] = v;
    }
    for (int i = 0; i < 3; i++) {
        float s = 0.f;
        #pragma unroll
        for (int j = 0; j < 2; j++) {
            const int c = t + j * 256;
            if (c < C4) {
                const float4 wv = cw4[i * C4 + c];
                s += xv[j].x * wv.x + xv[j].y * wv.y + xv[j].z * wv.z + xv[j].w * wv.w;
            }
        }
        #pragma unroll
        for (int off = 32; off > 0; off >>= 1) s += __shfl_down(s, off, 64);
        if (lane == 0) red[i & 1][w] = s;
        __syncthreads();
        const float st = red[i & 1][0] + red[i & 1][1] + red[i & 1][2] + red[i & 1][3];
        #pragma unroll
        for (int j = 0; j < 2; j++) {
            const int c = t + j * 256;
            if (c < C4) {
                const float4 bv = cb4[i * C4 + c];
                xv[j].x = x0v[j].x * st + bv.x + xv[j].x;
                xv[j].y = x0v[j].y * st + bv.y + xv[j].y;
                xv[j].z = x0v[j].z * st + bv.z + xv[j].z;
                xv[j].w = x0v[j].w * st + bv.w + xv[j].w;
            }
        }
    }
    float s = 0.f;
    #pragma unroll
    for (int j = 0; j < 2; j++) {
        const int c = t + j * 256;
        if (c < C4) {
            const float4 wv = ow4[c];
            s += xv[j].x * wv.x + xv[j].y * wv.y + xv[j].z * wv.z + xv[j].w * wv.w;
        }
    }
    #pragma unroll
    for (int off = 32; off > 0; off >>= 1) s += __shfl_down(s, off, 64);
    if (lane == 0) red[1][w] = s;
    __syncthreads();
    if (t == 0) partial[b] = red[1][0] + red[1][1] + red[1][2] + red[1][3];
}

// ------------------------------------------------ GEMM1: pipelined 128x64
// h1 = relu(x0b[4096,1664] @ w1t[1024,1664]^T + b1), bf16 in/out.
// T3+T4: 2-deep LDS double-buffer, counted vmcnt(6) (never drain in-loop),
// raw s_barrier. T2: source-pre-swizzled LDS slots -> 2-way-free ds_read_b128
// (old layout was 8-way conflicted: 64B row stride).
// Swizzle: chunk = 16 rows x 32 cols; slot(R,s) holds data col-block
// s ^ ((R>>1)&3). Write side: lane i -> slot i, so its GLOBAL col-block is
// (i&3)^((i>>3)&3). Read side: data col-block C=l>>4 sits at stored col
// C ^ ((l>>1)&3). Both are lane constants (zero inner-loop cost).
__global__ __launch_bounds__(256, 2) void gemm1_pipe(
        const unsigned short* __restrict__ A,
        const unsigned short* __restrict__ Bt,
        const float* __restrict__ bias,
        unsigned short* __restrict__ C)
{
    constexpr int M = B_, N = N1_, K = D_;
    constexpr int BM = 128, BN = 64, BKC = 64, KU = BKC / 32;
    constexpr int nA = BM / 16, nB = BN / 16, nAB = nA + nB;   // 8,4,12
    constexpr int TOTC = KU * nAB;                              // 24 chunks
    constexpr int T = K / BKC;                                  // 26 steps
    constexpr int LPW = TOTC / 4;                               // 6 loads/wave
    static_assert(LPW == 6 && (nA % 4) == 0, "chunk schedule");

    __shared__ unsigned short sA[2][KU * BM * 32];   // 2 x 16 KB
    __shared__ unsigned short sB[2][KU * BN * 32];   // 2 x  8 KB

    const int t    = threadIdx.x;
    const int lane = t & 63;
    const int w    = t >> 6;

    // XCD swizzle over grid (16, 32) = 512 blocks
    const int i    = blockIdx.y * gridDim.x + blockIdx.x;
    const int xcd  = i & 7;
    const int s    = i >> 3;
    const int ypg  = gridDim.y >> 3;
    const int ty   = xcd * ypg + s / gridDim.x;
    const int tx   = s - (s / gridDim.x) * gridDim.x;
    const int m0   = ty * BM;
    const int n0   = tx * BN;
    const int wm   = (w >> 1) * 64;    // 2x2 waves, 64x32 each
    const int wn   = (w & 1) * 32;

    // staging lane constants (global source col pre-swizzled)
    const int srow = lane >> 2;
    const int scol = ((lane & 3) ^ ((lane >> 3) & 3)) * 8;
    // read lane constant (stored col-block for data block l>>4)
    const int rcol = (((lane >> 4) ^ ((lane >> 1) & 3))) * 8;

    f32x4 acc[4][2] = {};

    auto STAGE = [&](int kt, int bsel) {
        const int k0 = kt * BKC;
        #pragma unroll
        for (int c0 = 0; c0 < TOTC; c0 += 4) {
            const int c = c0 + w;
            const int u = c / nAB;              // wave-uniform (groups of 4)
            const int r = c - u * nAB;
            if (r < nA) {
                const unsigned short* g =
                    A + (size_t)(m0 + r * 16 + srow) * K + k0 + u * 32 + scol;
                async_load16(g, &sA[bsel][u * BM * 32 + r * 512]);
            } else {
                const int rb = r - nA;
                const unsigned short* g =
                    Bt + (size_t)(n0 + rb * 16 + srow) * K + k0 + u * 32 + scol;
                async_load16(g, &sB[bsel][u * BN * 32 + rb * 512]);
            }
        }
    };

    STAGE(0, 0);
    for (int kt = 0; kt < T; kt++) {
        const int cur = kt & 1;
        if (kt + 1 < T) {
            STAGE(kt + 1, cur ^ 1);
            asm volatile("s_waitcnt vmcnt(6)" ::: "memory");  // own next-tile loads stay in flight
        } else {
            asm volatile("s_waitcnt vmcnt(0)" ::: "memory");
        }
        __builtin_amdgcn_s_barrier();            // all waves' cur-tile loads landed
        __builtin_amdgcn_sched_barrier(0);
        #pragma unroll
        for (int u = 0; u < KU; u++) {
            bf16x8 af[4], bfr[2];
            #pragma unroll
            for (int ii = 0; ii < 4; ii++)
                af[ii] = *(const bf16x8*)
                    &sA[cur][u * BM * 32 + (wm + ii * 16 + (lane & 15)) * 32 + rcol];
            #pragma unroll
            for (int j = 0; j < 2; j++)
                bfr[j] = *(const bf16x8*)
                    &sB[cur][u * BN * 32 + (wn + j * 16 + (lane & 15)) * 32 + rcol];
            #pragma unroll
            for (int ii = 0; ii < 4; ii++)
                #pragma unroll
                for (int j = 0; j < 2; j++)
                    acc[ii][j] = mfma16(af[ii], bfr[j], acc[ii][j]);
        }
        __builtin_amdgcn_s_barrier();            // cur buffer free for kt+2's STAGE
    }

    // epilogue: C/D layout col=lane&15, row=(lane>>4)*4+reg
    #pragma unroll
    for (int ii = 0; ii < 4; ii++) {
        const int r0 = m0 + wm + ii * 16 + (lane >> 4) * 4;
        #pragma unroll
        for (int j = 0; j < 2; j++) {
            const int col = n0 + wn + j * 16 + (lane & 15);
            const float bv = bias[col];
            #pragma unroll
            for (int r = 0; r < 4; r++) {
                float v = acc[ii][j][r] + bv;
                v = fmaxf(v, 0.f);
                C[(size_t)(r0 + r) * N + col] = f2b(v);
            }
        }
    }
}

// ------------------------------------------------------------- MFMA GEMM
// (R2 template, unchanged) used for layers 2 and 3.
template<int BM, int BN, int BKC>
__global__ __launch_bounds__(256, 4) void gemm_bias_relu(
        const unsigned short* __restrict__ A,
        const unsigned short* __restrict__ Bt,
        const float* __restrict__ bias,
        unsigned short* __restrict__ C,
        int M, int N, int K)
{
    constexpr int KU = BKC / 32;
    constexpr int WM = BM / 2, WN = BN / 2;
    constexpr int TI = WM / 16, TJ = WN / 16;
    constexpr int nA = BM / 16, nB = BN / 16, nAB = nA + nB;
    constexpr int TOTC = KU * nAB;
    static_assert(TOTC % 4 == 0, "chunk loop assumes 4-wave coverage");

    __shared__ unsigned short sA[KU * BM * 32];
    __shared__ unsigned short sB[KU * BN * 32];

    const int t    = threadIdx.x;
    const int lane = t & 63;
    const int w    = t >> 6;

    const int i    = blockIdx.y * gridDim.x + blockIdx.x;
    const int xcd  = i & 7;
    const int s    = i >> 3;
    const int ypg  = gridDim.y >> 3;
    const int ty   = xcd * ypg + s / gridDim.x;
    const int tx   = s - (s / gridDim.x) * gridDim.x;
    const int m0   = ty * BM;
    const int n0   = tx * BN;
    const int wm   = (w >> 1) * WM;
    const int wn   = (w & 1) * WN;

    const int srow = lane >> 2;
    const int scol = (lane & 3) * 8;

    f32x4 acc[TI][TJ] = {};

    for (int k0 = 0; k0 < K; k0 += BKC) {
        #pragma unroll
        for (int c0 = 0; c0 < TOTC; c0 += 4) {
            const int c = c0 + w;
            const int u = c / nAB;
            const int r = c - u * nAB;
            if (r < nA) {
                const unsigned short* g =
                    A + (size_t)(m0 + r * 16 + srow) * K + k0 + u * 32 + scol;
                async_load16(g, &sA[u * BM * 32 + r * 512]);
            } else {
                const int rb = r - nA;
                const unsigned short* g =
                    Bt + (size_t)(n0 + rb * 16 + srow) * K + k0 + u * 32 + scol;
                async_load16(g, &sB[u * BN * 32 + rb * 512]);
            }
        }
        __syncthreads();

        #pragma unroll
        for (int u = 0; u < KU; u++) {
            bf16x8 af[TI], bf[TJ];
            #pragma unroll
            for (int ii = 0; ii < TI; ii++)
                af[ii] = *(const bf16x8*)
                    &sA[u * BM * 32 + (wm + ii * 16 + (lane & 15)) * 32 + (lane >> 4) * 8];
            #pragma unroll
            for (int j = 0; j < TJ; j++)
                bf[j] = *(const bf16x8*)
                    &sB[u * BN * 32 + (wn + j * 16 + (lane & 15)) * 32 + (lane >> 4) * 8];
            #pragma unroll
            for (int ii = 0; ii < TI; ii++)
                #pragma unroll
                for (int j = 0; j < TJ; j++)
                    acc[ii][j] = mfma16(af[ii], bf[j], acc[ii][j]);
        }
        __syncthreads();
    }

    #pragma unroll
    for (int ii = 0; ii < TI; ii++) {
        const int r0 = m0 + wm + ii * 16 + (lane >> 4) * 4;
        #pragma unroll
        for (int j = 0; j < TJ; j++) {
            const int col = n0 + wn + j * 16 + (lane & 15);
            const float bv = bias[col];
            #pragma unroll
            for (int r = 0; r < 4; r++) {
                float v = acc[ii][j][r] + bv;
                v = fmaxf(v, 0.f);
                C[(size_t)(r0 + r) * N + col] = f2b(v);
            }
        }
    }
}

// ---------------------------------------------------------------- head
__global__ __launch_bounds__(256) void head_kernel(
        const float* __restrict__ partial, const unsigned short* __restrict__ h3,
        const float* __restrict__ out_w, const float* __restrict__ out_b,
        float* __restrict__ out)
{
    const int gw   = (blockIdx.x * 256 + threadIdx.x) >> 6;
    const int lane = threadIdx.x & 63;
    if (gw >= B_) return;
    float s = 0.f;
    #pragma unroll
    for (int q = 0; q < 4; q++) {
        const int j = lane + q * 64;
        s += b2f(h3[(size_t)gw * N3_ + j]) * out_w[D_ + j];
    }
    #pragma unroll
    for (int off = 32; off > 0; off >>= 1) s += __shfl_down(s, off, 64);
    if (lane == 0) {
        const float logit = partial[gw] + s + out_b[0];
        out[gw] = 1.f / (1.f + expf(-logit));
    }
}

extern "C" void kernel_launch(void* const* d_in, const int* in_sizes, int n_in,
                              void* d_out, int out_size, void* d_ws, size_t ws_size,
                              hipStream_t stream)
{
    (void)in_sizes; (void)n_in; (void)out_size; (void)ws_size;
    const int*   ids     = (const int*)  d_in[0];
    const float* emb     = (const float*)d_in[1];
    const float* cross_w = (const float*)d_in[2];
    const float* cross_b = (const float*)d_in[3];
    const float* w1      = (const float*)d_in[4];
    const float* b1      = (const float*)d_in[5];
    const float* w2      = (const float*)d_in[6];
    const float* b2      = (const float*)d_in[7];
    const float* w3      = (const float*)d_in[8];
    const float* b3      = (const float*)d_in[9];
    const float* out_w   = (const float*)d_in[10];
    const float* out_b   = (const float*)d_in[11];
    float* out = (float*)d_out;

    char* p = (char*)d_ws;
    auto alloc = [&](size_t bytes) {
        char* r = p; p += (bytes + 255) & ~(size_t)255; return r;
    };
    unsigned short* x0b = (unsigned short*)alloc((size_t)B_ * D_ * 2);
    unsigned short* w1t = (unsigned short*)alloc((size_t)D_ * N1_ * 2);
    unsigned short* w2t = (unsigned short*)alloc((size_t)N1_ * N2_ * 2);
    unsigned short* w3t = (unsigned short*)alloc((size_t)N2_ * N3_ * 2);
    unsigned short* h1  = (unsigned short*)alloc((size_t)B_ * N1_ * 2);
    unsigned short* h2  = (unsigned short*)alloc((size_t)B_ * N2_ * 2);
    unsigned short* h3  = (unsigned short*)alloc((size_t)B_ * N3_ * 2);
    float* partial      = (float*)alloc((size_t)B_ * 4);

    gather_cross_transpose_kernel<<<B_ + 2304, 256, 0, stream>>>(
        ids, emb, cross_w, cross_b, out_w, x0b, partial,
        w1, w2, w3, w1t, w2t, w3t);

    // layer 1: pipelined 128x64 (512 blocks, 2/CU, dbuf + counted vmcnt)
    gemm1_pipe<<<dim3(N1_ / 64, B_ / 128), 256, 0, stream>>>(x0b, w1t, b1, h1);
    // layers 2-3: R2 config (1024 blocks, 4/CU, BKC=128)
    gemm_bias_relu<64, 32, 128><<<dim3(N2_ / 32, B_ / 64), 256, 0, stream>>>(
        h1, w2t, b2, h2, B_, N2_, N1_);
    gemm_bias_relu<32, 32, 128><<<dim3(N3_ / 32, B_ / 32), 256, 0, stream>>>(
        h2, w3t, b3, h3, B_, N3_, N2_);

    head_kernel<<<B_ / 4, 256, 0, stream>>>(partial, h3, out_w, out_b, out);
}